// Round 5
// baseline (367.854 us; speedup 1.0000x reference)
//
#include <hip/hip_runtime.h>
#include <cstdint>
#include <cstddef>

typedef unsigned short u16;
typedef __attribute__((ext_vector_type(8))) short s16x8;
typedef __attribute__((ext_vector_type(4))) float f32x4;

#define DEV __device__ __forceinline__

DEV float bf2f(short u){
  union { unsigned int i; float f; } v;
  v.i = ((unsigned int)(u16)u) << 16;
  return v.f;
}
DEV short f2bf(float f){
  union { float f; unsigned int i; } v; v.f = f;
  unsigned int u = v.i;
  u += 0x7fffu + ((u >> 16) & 1u);   // RNE
  return (short)(u >> 16);
}
DEV s16x8 s16x8_zero(){
  s16x8 z;
#pragma unroll
  for(int j=0;j<8;j++) z[j]=0;
  return z;
}
DEV f32x4 f32x4_zero(){
  f32x4 z;
#pragma unroll
  for(int j=0;j<4;j++) z[j]=0.f;
  return z;
}
DEV f32x4 mfma16(s16x8 a, s16x8 b, f32x4 c){
  return __builtin_amdgcn_mfma_f32_16x16x32_bf16(a, b, c, 0, 0, 0);
}
// LDS-only barrier: drains lgkm (ds ops) but leaves global loads in flight (T3/T4).
DEV void bar_lds(){
  asm volatile("s_waitcnt lgkmcnt(0)");
  __builtin_amdgcn_s_barrier();
}
DEV void wait_vm4(){ asm volatile("s_waitcnt vmcnt(4)" ::: "memory"); }
DEV void wait_vm1(){ asm volatile("s_waitcnt vmcnt(1)" ::: "memory"); }
// async global -> LDS, 16 B per lane; lds dst must be wave-uniform base (+lane*16 implicit)
DEV void gload16(const u16* g, u16* l){
  __builtin_amdgcn_global_load_lds(
      (const __attribute__((address_space(1))) unsigned int*)g,
      (__attribute__((address_space(3))) unsigned int*)l, 16, 0, 0);
}

// ---------------- problem constants ----------------
// B=4, Cin=512 (concat), H=W=64, P=9 taps, Cout=256, M = B*H*W = 16384
static constexpr size_t OFF_ACC_B  = 0;                        // float[16384*32] (atomic-accumulated)
static constexpr size_t STATS_B    = 2097152;                  // float[1024]
static constexpr size_t ZERO_BYTES = STATS_B + 4096;           // only off_acc + stats need zeroing
static constexpr size_t OUT1_ACC_B = ZERO_BYTES;               // float[16384*256] (fully overwritten)
static constexpr size_t OUT2_ACC_B = OUT1_ACC_B + 16777216;    // float[16384*256] (fully overwritten)
static constexpr size_t XN_B       = OUT2_ACC_B + 16777216;    // u16[16384*512]
static constexpr size_t OUT1N_B    = XN_B + 16777216;          // u16[16384*256]
static constexpr size_t WOFFT_B    = OUT1N_B + 8388608;        // u16[32*4608]
static constexpr size_t WDCNT_B    = WOFFT_B + 294912;         // u16[256*4608]
static constexpr size_t W2T_B      = WDCNT_B + 2359296;        // u16[256*2304]

// ---------------- NCHW fp32 (concat) -> NHWC bf16 ----------------
__global__ void k_x_to_nhwc(const float* __restrict__ v, const float* __restrict__ vi,
                            u16* __restrict__ xn){
  __shared__ float tile[64][65];
  const int b = blockIdx.z, c0 = blockIdx.y*64, hw0 = blockIdx.x*64;
  const float* src = (c0 < 256) ? (v  + ((size_t)b*256 + c0)      *4096)
                                : (vi + ((size_t)b*256 + (c0-256))*4096);
  const int t = threadIdx.x;
#pragma unroll
  for(int k=0;k<16;k++){
    int idx = t + k*256;
    int cl = idx >> 6, wl = idx & 63;
    tile[cl][wl] = src[(size_t)cl*4096 + hw0 + wl];
  }
  __syncthreads();
#pragma unroll
  for(int k=0;k<16;k++){
    int idx = t + k*256;
    int wl = idx >> 6, cl = idx & 63;
    xn[(size_t)(b*4096 + hw0 + wl)*512 + c0 + cl] = (u16)f2bf(tile[cl][wl]);
  }
}

// ---------------- weight repacks: OIHW fp32 -> [N][K] bf16, K = tap*C + c ----------------
__global__ void k_prep_woff(const float* __restrict__ w, u16* __restrict__ wt){
  int idx = blockIdx.x*256 + threadIdx.x;
  if(idx >= 32*4608) return;
  int n = idx / 4608, k = idx % 4608;
  int t = k >> 9, c = k & 511;
  float val = (n < 27) ? w[(size_t)(n*512 + c)*9 + t] : 0.f;
  wt[idx] = (u16)f2bf(val);
}
__global__ void k_prep_wdcn(const float* __restrict__ w, u16* __restrict__ wt){
  int idx = blockIdx.x*256 + threadIdx.x;
  if(idx >= 256*4608) return;
  int n = idx / 4608, k = idx % 4608;
  int t = k >> 9, c = k & 511;
  wt[idx] = (u16)f2bf(w[(size_t)(n*512 + c)*9 + t]);
}
__global__ void k_prep_w2(const float* __restrict__ w, u16* __restrict__ wt){
  int idx = blockIdx.x*256 + threadIdx.x;
  if(idx >= 256*2304) return;
  int n = idx / 2304, k = idx % 2304;
  int t = k >> 8, c = k & 255;
  wt[idx] = (u16)f2bf(w[(size_t)(n*256 + c)*9 + t]);
}

// ---------------- offset conv: 512ch -> 27(pad 32), implicit GEMM (R3 structure) ----------------
__global__ __launch_bounds__(256, 2) void k_conv_off(
    const u16* __restrict__ xn, const u16* __restrict__ wt, float* __restrict__ offa){
  __shared__ short A_lds[4][128][8];
  __shared__ short B_lds[4][32][8];
  const int tid = threadIdx.x;
  const int lane = tid & 63, wid = tid >> 6;
  const int quad = lane >> 4, ln = lane & 15;
  const int m0 = blockIdx.x * 128;
  const int b = m0 >> 12;
  const int h0 = (m0 & 4095) >> 6;
  const int ks = blockIdx.y;
  const int ts0 = (ks == 3) ? 6 : ks*2;
  const int ntap = (ks == 3) ? 3 : 2;
  const int m_base = wid * 32;
  const int r = tid >> 1, sp = (tid & 1) * 2;
  const int h_r = h0 + (r >> 6), w_r = r & 63;
  const s16x8* Ap = (const s16x8*)A_lds;
  const s16x8* Bp = (const s16x8*)B_lds;
  f32x4 acc[2][2];
#pragma unroll
  for(int mf=0;mf<2;mf++)
#pragma unroll
    for(int nf=0;nf<2;nf++) acc[mf][nf] = f32x4_zero();

  auto load_it = [&](int it, s16x8& v0, s16x8& v1, s16x8& bv){
    const int tp = ts0 + (it >> 4);
    const int cA = (it & 15)*32;
    const int ty = tp/3, tx = tp - ty*3;
    const int y = h_r - 1 + ty, x = w_r - 1 + tx;
    const bool vld = (y>=0) & (y<64) & (x>=0) & (x<64);
    v0 = s16x8_zero(); v1 = s16x8_zero();
    if(vld){
      const u16* src = xn + ((size_t)((b<<12) + (y<<6) + x) << 9) + cA + sp*8;
      v0 = *(const s16x8*)(src);
      v1 = *(const s16x8*)(src + 8);
    }
    if(tid < 128){
      const int n = tid & 31, s2 = tid >> 5;
      bv = *(const s16x8*)(wt + (size_t)n*4608 + tp*512 + cA + s2*8);
    }
  };

  const int NIT = ntap * 16;
  s16x8 v0a, v1a, bva, v0b, v1b, bvb;
  bva = s16x8_zero(); bvb = s16x8_zero();
  load_it(0, v0a, v1a, bva);
  load_it(1, v0b, v1b, bvb);
  for(int it = 0; it < NIT; it += 2){
    bar_lds();
    *(s16x8*)(&A_lds[sp][r][0])   = v0a;
    *(s16x8*)(&A_lds[sp+1][r][0]) = v1a;
    if(tid < 128){
      const int n = tid & 31, s2 = tid >> 5;
      *(s16x8*)(&B_lds[s2][n][0]) = bva;
    }
    if(it + 2 < NIT) load_it(it + 2, v0a, v1a, bva);
    bar_lds();
    {
      s16x8 a0 = Ap[quad*128 + m_base + ln];
      s16x8 a1 = Ap[quad*128 + m_base + 16 + ln];
      s16x8 b0 = Bp[quad*32 + ln];
      s16x8 b1 = Bp[quad*32 + 16 + ln];
      acc[0][0] = mfma16(a0, b0, acc[0][0]);
      acc[0][1] = mfma16(a0, b1, acc[0][1]);
      acc[1][0] = mfma16(a1, b0, acc[1][0]);
      acc[1][1] = mfma16(a1, b1, acc[1][1]);
    }
    bar_lds();
    *(s16x8*)(&A_lds[sp][r][0])   = v0b;
    *(s16x8*)(&A_lds[sp+1][r][0]) = v1b;
    if(tid < 128){
      const int n = tid & 31, s2 = tid >> 5;
      *(s16x8*)(&B_lds[s2][n][0]) = bvb;
    }
    if(it + 3 < NIT) load_it(it + 3, v0b, v1b, bvb);
    bar_lds();
    {
      s16x8 a0 = Ap[quad*128 + m_base + ln];
      s16x8 a1 = Ap[quad*128 + m_base + 16 + ln];
      s16x8 b0 = Bp[quad*32 + ln];
      s16x8 b1 = Bp[quad*32 + 16 + ln];
      acc[0][0] = mfma16(a0, b0, acc[0][0]);
      acc[0][1] = mfma16(a0, b1, acc[0][1]);
      acc[1][0] = mfma16(a1, b0, acc[1][0]);
      acc[1][1] = mfma16(a1, b1, acc[1][1]);
    }
  }
#pragma unroll
  for(int mf=0;mf<2;mf++)
#pragma unroll
    for(int nf=0;nf<2;nf++){
      const int col = nf*16 + ln;
#pragma unroll
      for(int i=0;i<4;i++){
        const int row = m_base + mf*16 + quad*4 + i;
        unsafeAtomicAdd(offa + (size_t)(m0+row)*32 + col, acc[mf][nf][i]);
      }
    }
}

// ---------------- DCN main: 64x256 tile, full K=4608, dbuf LDS, 1 barrier/phase ----------------
// grid 256 blocks (1 m-tile each), 512 threads (8 waves = 2m x 4n)
__global__ __launch_bounds__(512, 1) void k_dcn(
    const u16* __restrict__ xn, const u16* __restrict__ wt,
    const float* __restrict__ offa, const float* __restrict__ boff,
    float* __restrict__ outa){
  __shared__ short A_lds[2][8][64][8];    // 16 KB: [buf][k-slice][row][8]
  __shared__ short B_lds[2][8][256][8];   // 64 KB: [buf][k-slice][n][8]
  __shared__ int   p_ofs[9][4][64];       // 9 KB
  __shared__ float p_wgt[9][4][64];       // 9 KB
  const int tid = threadIdx.x;
  const int lane = tid & 63, wid = tid >> 6;
  const int quad = lane >> 4, ln = lane & 15;
  const int wm = wid >> 2, wn = wid & 3;   // wave tile: 32m x 64n
  const int m0 = blockIdx.x * 64;
  const int b = m0 >> 12;
  const int h = (m0 & 4095) >> 6;
  const int r_s = tid >> 3, sub = tid & 7; // staging: row, k-slice
  constexpr int NP = 72;                   // 9 taps x 8 chunks of 64 ch
  f32x4 acc[2][4];
#pragma unroll
  for(int mf=0;mf<2;mf++)
#pragma unroll
    for(int nf=0;nf<4;nf++) acc[mf][nf] = f32x4_zero();

  // ---- one-time: bilinear offsets/weights for all 9 taps ----
  {
    const int rr = tid & 63;
    const float* orow = offa + (size_t)(m0+rr)*32;
    for(int tp = tid >> 6; tp < 9; tp += 8){
      float dy = orow[2*tp]   + boff[2*tp];
      float dx = orow[2*tp+1] + boff[2*tp+1];
      float mz = orow[18+tp]  + boff[18+tp];
      float mk = 1.f / (1.f + expf(-mz));
      float ypos = (float)(h - 1 + tp/3) + dy;
      float xpos = (float)(rr - 1 + tp%3) + dx;
      float y0f = floorf(ypos), x0f = floorf(xpos);
      float ly = ypos - y0f, lx = xpos - x0f;
      int y0 = (int)y0f, x0 = (int)x0f;
#pragma unroll
      for(int k=0;k<4;k++){
        int ddy = k >> 1, ddx = k & 1;
        int yi = y0 + ddy, xi = x0 + ddx;
        bool vv = (yi >= 0) & (yi < 64) & (xi >= 0) & (xi < 64);
        float wk = (ddy ? ly : 1.f-ly) * (ddx ? lx : 1.f-lx) * mk;
        if(!vv) wk = 0.f;
        int yc = yi < 0 ? 0 : (yi > 63 ? 63 : yi);
        int xc = xi < 0 ? 0 : (xi > 63 ? 63 : xi);
        p_ofs[tp][k][rr] = ((b << 12) + (yc << 6) + xc) << 9;  // *512 channels
        p_wgt[tp][k][rr] = wk;
      }
    }
  }
  __syncthreads();

  auto gather = [&](int t, s16x8* g){                 // 4 neighbor loads -> regs
    const int tp = t >> 3;
    const int kcc = (t & 7)*64 + sub*8;
#pragma unroll
    for(int k=0;k<4;k++)
      g[k] = *(const s16x8*)(xn + p_ofs[tp][k][r_s] + kcc);
  };
  auto blendw = [&](int t, const s16x8* g){           // weighted blend -> bf16x8
    const int tp = t >> 3;
    const float w0 = p_wgt[tp][0][r_s], w1 = p_wgt[tp][1][r_s];
    const float w2 = p_wgt[tp][2][r_s], w3 = p_wgt[tp][3][r_s];
    s16x8 pk;
#pragma unroll
    for(int j=0;j<8;j++){
      float f = w0 * bf2f(g[0][j]);
      f = fmaf(w1, bf2f(g[1][j]), f);
      f = fmaf(w2, bf2f(g[2][j]), f);
      f = fmaf(w3, bf2f(g[3][j]), f);
      pk[j] = f2bf(f);
    }
    return pk;
  };
  auto stageB = [&](int t, int bi){                   // 4 global_load_lds per wave
    const int tp = t >> 3, kc = (t & 7)*64;
#pragma unroll
    for(int i=0;i<4;i++){
      const int li = wid*4 + i;
      const int sl = li >> 2, n0 = (li & 3)*64;
      gload16(wt + (size_t)(n0 + lane)*4608 + tp*512 + kc + sl*8,
              (u16*)&B_lds[bi][sl][n0][0]);
    }
  };
  auto phase = [&](int t, int cur, const s16x8* gB, s16x8* gF){
    const int nxt = cur ^ 1;
    if(t + 1 < NP){
      s16x8 pk = blendw(t + 1, gB);                   // consumes gathers issued @ t-1
      *(s16x8*)&A_lds[nxt][sub][r_s][0] = pk;         // ds_write next buffer
      stageB(t + 1, nxt);                             // B -> next buffer (vmcnt)
    }
    __builtin_amdgcn_sched_barrier(0);                // pin B-issue before A-issue
    if(t + 2 < NP) gather(t + 2, gF);                 // A prefetch ~1.5 phases ahead
    // compute on current buffer (overlaps staging writes above)
#pragma unroll
    for(int kk=0;kk<2;kk++){
      s16x8 af0 = *(const s16x8*)&A_lds[cur][kk*4+quad][wm*32 + ln][0];
      s16x8 af1 = *(const s16x8*)&A_lds[cur][kk*4+quad][wm*32 + 16 + ln][0];
      s16x8 bf[4];
#pragma unroll
      for(int nf=0;nf<4;nf++)
        bf[nf] = *(const s16x8*)&B_lds[cur][kk*4+quad][wn*64 + nf*16 + ln][0];
#pragma unroll
      for(int nf=0;nf<4;nf++){
        acc[0][nf] = mfma16(af0, bf[nf], acc[0][nf]);
        acc[1][nf] = mfma16(af1, bf[nf], acc[1][nf]);
      }
    }
    wait_vm4();        // B(t+1) landed; A(t+2) gathers (4) stay in flight
    bar_lds();         // single barrier per phase
  };

  // ---- warmup: fill buf0 and both gather sets
  s16x8 S0[4], S1[4];
  gather(0, S0);
  stageB(0, 0);
  __builtin_amdgcn_sched_barrier(0);
  gather(1, S1);
  {
    s16x8 pk = blendw(0, S0);
    *(s16x8*)&A_lds[0][sub][r_s][0] = pk;
  }
  wait_vm4();          // B(0) landed; A(1) in flight
  bar_lds();

  for(int t = 0; t < NP; t += 2){
    phase(t,     0, S1, S0);
    phase(t + 1, 1, S0, S1);
  }

  // ---- epilogue: plain stores (no split-K, no atomics)
#pragma unroll
  for(int mf=0;mf<2;mf++)
#pragma unroll
    for(int nf=0;nf<4;nf++){
      const int col = wn*64 + nf*16 + ln;
#pragma unroll
      for(int i=0;i<4;i++){
        const int row = m0 + wm*32 + mf*16 + quad*4 + i;
        outa[(size_t)row*256 + col] = acc[mf][nf][i];
      }
    }
}

// ---------------- conv2: 256 -> 256, 64x256 tile, full K=2304, dbuf LDS ----------------
// grid 256 blocks, 512 threads (8 waves = 2m x 4n)
__global__ __launch_bounds__(512, 1) void k_conv2(
    const u16* __restrict__ a_in, const u16* __restrict__ wt, float* __restrict__ outa){
  __shared__ short A_lds[2][8][64][8];    // 16 KB
  __shared__ short B_lds[2][8][256][8];   // 64 KB
  const int tid = threadIdx.x;
  const int lane = tid & 63, wid = tid >> 6;
  const int quad = lane >> 4, ln = lane & 15;
  const int wm = wid >> 2, wn = wid & 3;
  const int m0 = blockIdx.x * 64;
  const int b = m0 >> 12;
  const int h = (m0 & 4095) >> 6;
  const int r_s = tid >> 3, sub = tid & 7;
  constexpr int NP = 36;                   // 9 taps x 4 chunks of 64 ch
  f32x4 acc[2][4];
#pragma unroll
  for(int mf=0;mf<2;mf++)
#pragma unroll
    for(int nf=0;nf<4;nf++) acc[mf][nf] = f32x4_zero();

  auto loadA = [&](int t, s16x8& va){
    const int tp = t >> 2;
    const int ty = tp/3, tx = tp - ty*3;
    const int y = h - 1 + ty, x = r_s - 1 + tx;
    const bool vld = (y>=0) & (y<64) & (x>=0) & (x<64);
    va = s16x8_zero();
    if(vld)
      va = *(const s16x8*)(a_in + (((size_t)((b<<12) + (y<<6) + x)) << 8)
                           + (t & 3)*64 + sub*8);
  };
  auto stageB = [&](int t, int bi){
    const int tp = t >> 2, kc = (t & 3)*64;
#pragma unroll
    for(int i=0;i<4;i++){
      const int li = wid*4 + i;
      const int sl = li >> 2, n0 = (li & 3)*64;
      gload16(wt + (size_t)(n0 + lane)*2304 + tp*256 + kc + sl*8,
              (u16*)&B_lds[bi][sl][n0][0]);
    }
  };
  auto phase = [&](int t, int cur, const s16x8& vB, s16x8& vF){
    const int nxt = cur ^ 1;
    if(t + 1 < NP){
      *(s16x8*)&A_lds[nxt][sub][r_s][0] = vB;
      stageB(t + 1, nxt);
    }
    __builtin_amdgcn_sched_barrier(0);
    if(t + 2 < NP) loadA(t + 2, vF);
#pragma unroll
    for(int kk=0;kk<2;kk++){
      s16x8 af0 = *(const s16x8*)&A_lds[cur][kk*4+quad][wm*32 + ln][0];
      s16x8 af1 = *(const s16x8*)&A_lds[cur][kk*4+quad][wm*32 + 16 + ln][0];
      s16x8 bf[4];
#pragma unroll
      for(int nf=0;nf<4;nf++)
        bf[nf] = *(const s16x8*)&B_lds[cur][kk*4+quad][wn*64 + nf*16 + ln][0];
#pragma unroll
      for(int nf=0;nf<4;nf++){
        acc[0][nf] = mfma16(af0, bf[nf], acc[0][nf]);
        acc[1][nf] = mfma16(af1, bf[nf], acc[1][nf]);
      }
    }
    wait_vm1();        // B(t+1) landed; A(t+2) (1 load) in flight
    bar_lds();
  };

  s16x8 S0, S1;
  loadA(0, S0);
  stageB(0, 0);
  __builtin_amdgcn_sched_barrier(0);
  loadA(1, S1);
  *(s16x8*)&A_lds[0][sub][r_s][0] = S0;
  wait_vm1();
  bar_lds();

  for(int t = 0; t < NP; t += 2){
    phase(t,     0, S1, S0);
    phase(t + 1, 1, S0, S1);
  }

#pragma unroll
  for(int mf=0;mf<2;mf++)
#pragma unroll
    for(int nf=0;nf<4;nf++){
      const int col = wn*64 + nf*16 + ln;
#pragma unroll
      for(int i=0;i<4;i++){
        const int row = m0 + wm*32 + mf*16 + quad*4 + i;
        outa[(size_t)row*256 + col] = acc[mf][nf][i];
      }
    }
}

// ---------------- BN stats: per-channel sum/sumsq over M=16384 ----------------
__global__ void k_stats(const float* __restrict__ acc, float* __restrict__ sum,
                        float* __restrict__ sq){
  const int m0 = blockIdx.x*64;
  const int c = threadIdx.x;
  float s = 0.f, q = 0.f;
  for(int i=0;i<64;i++){
    float v = acc[(size_t)(m0+i)*256 + c];
    s += v; q += v*v;
  }
  unsafeAtomicAdd(sum + c, s);
  unsafeAtomicAdd(sq + c, q);
}

// ---------------- BN1 + ReLU -> bf16 NHWC ----------------
__global__ void k_bn1(const float* __restrict__ acc, const float* __restrict__ sum,
                      const float* __restrict__ sq, const float* __restrict__ g,
                      const float* __restrict__ bt, u16* __restrict__ o){
  __shared__ float sc[256], sh[256];
  const int t = threadIdx.x;
  {
    float mean = sum[t] * (1.f/16384.f);
    float var  = sq[t] * (1.f/16384.f) - mean*mean;
    float rstd = rsqrtf(var + 1e-5f);
    float s = g[t] * rstd;
    sc[t] = s; sh[t] = bt[t] - mean*s;
  }
  __syncthreads();
  const int c4 = (t & 63) * 4;
  const float s0 = sc[c4], s1 = sc[c4+1], s2 = sc[c4+2], s3 = sc[c4+3];
  const float h0 = sh[c4], h1 = sh[c4+1], h2 = sh[c4+2], h3 = sh[c4+3];
#pragma unroll
  for(int k=0;k<4;k++){
    int m = blockIdx.x*16 + k*4 + (t>>6);
    const float4 v = *(const float4*)(acc + (size_t)m*256 + c4);
    unsigned int lo = (unsigned int)(u16)f2bf(fmaxf(0.f, v.x*s0 + h0))
                    | ((unsigned int)(u16)f2bf(fmaxf(0.f, v.y*s1 + h1)) << 16);
    unsigned int hi = (unsigned int)(u16)f2bf(fmaxf(0.f, v.z*s2 + h2))
                    | ((unsigned int)(u16)f2bf(fmaxf(0.f, v.w*s3 + h3)) << 16);
    uint2 pr; pr.x = lo; pr.y = hi;
    *(uint2*)(o + (size_t)m*256 + c4) = pr;
  }
}

// ---------------- BN2 + ReLU + NHWC->NCHW fp32 output ----------------
__global__ void k_bn2_out(const float* __restrict__ acc, const float* __restrict__ sum,
                          const float* __restrict__ sq, const float* __restrict__ g,
                          const float* __restrict__ bt, float* __restrict__ out){
  __shared__ float tile[64][65];
  __shared__ float sc[64], sh[64];
  const int t = threadIdx.x;
  const int b = blockIdx.z, c0 = blockIdx.y*64, hw0 = blockIdx.x*64;
  if(t < 64){
    int c = c0 + t;
    float mean = sum[c] * (1.f/16384.f);
    float var  = sq[c] * (1.f/16384.f) - mean*mean;
    float rstd = rsqrtf(var + 1e-5f);
    float s = g[c] * rstd;
    sc[t] = s; sh[t] = bt[c] - mean*s;
  }
  __syncthreads();
#pragma unroll
  for(int k=0;k<16;k++){
    int idx = t + k*256;
    int wl = idx >> 6, cl = idx & 63;
    float v = acc[(size_t)((b<<12) + hw0 + wl)*256 + c0 + cl];
    tile[wl][cl] = fmaxf(0.f, v*sc[cl] + sh[cl]);
  }
  __syncthreads();
#pragma unroll
  for(int k=0;k<16;k++){
    int idx = t + k*256;
    int cl = idx >> 6, wl = idx & 63;
    out[(size_t)(b*256 + c0 + cl)*4096 + hw0 + wl] = tile[wl][cl];
  }
}

extern "C" void kernel_launch(void* const* d_in, const int* in_sizes, int n_in,
                              void* d_out, int out_size, void* d_ws, size_t ws_size,
                              hipStream_t stream){
  const float* in_v  = (const float*)d_in[0];
  const float* in_i  = (const float*)d_in[1];
  const float* w_off = (const float*)d_in[2];
  const float* b_off = (const float*)d_in[3];
  const float* w_dcn = (const float*)d_in[4];
  const float* g1    = (const float*)d_in[5];
  const float* bt1   = (const float*)d_in[6];
  const float* w2    = (const float*)d_in[7];
  const float* g2    = (const float*)d_in[8];
  const float* bt2   = (const float*)d_in[9];
  float* out = (float*)d_out;
  char* ws = (char*)d_ws;

  float* off_acc  = (float*)(ws + OFF_ACC_B);
  float* stats    = (float*)(ws + STATS_B);
  float* out1_acc = (float*)(ws + OUT1_ACC_B);
  float* out2_acc = (float*)(ws + OUT2_ACC_B);
  float* sum1 = stats,       *sq1 = stats + 256;
  float* sum2 = stats + 512, *sq2 = stats + 768;
  u16* xn    = (u16*)(ws + XN_B);
  u16* out1n = (u16*)(ws + OUT1N_B);
  u16* wofft = (u16*)(ws + WOFFT_B);
  u16* wdcnt = (u16*)(ws + WDCNT_B);
  u16* w2t   = (u16*)(ws + W2T_B);

  hipMemsetAsync(ws, 0, ZERO_BYTES, stream);
  k_x_to_nhwc<<<dim3(64,8,4), 256, 0, stream>>>(in_v, in_i, xn);
  k_prep_woff<<<576, 256, 0, stream>>>(w_off, wofft);
  k_prep_wdcn<<<4608, 256, 0, stream>>>(w_dcn, wdcnt);
  k_prep_w2<<<2304, 256, 0, stream>>>(w2, w2t);
  k_conv_off<<<dim3(128,4), 256, 0, stream>>>(xn, wofft, off_acc);
  k_dcn<<<256, 512, 0, stream>>>(xn, wdcnt, off_acc, b_off, out1_acc);
  k_stats<<<256, 256, 0, stream>>>(out1_acc, sum1, sq1);
  k_bn1<<<1024, 256, 0, stream>>>(out1_acc, sum1, sq1, g1, bt1, out1n);
  k_conv2<<<256, 512, 0, stream>>>(out1n, w2t, out2_acc);
  k_stats<<<256, 256, 0, stream>>>(out2_acc, sum2, sq2);
  k_bn2_out<<<dim3(64,4,4), 256, 0, stream>>>(out2_acc, sum2, sq2, g2, bt2, out);
}